// Round 12
// baseline (564.878 us; speedup 1.0000x reference)
//
#include <hip/hip_runtime.h>
#include <stdint.h>

// Problem constants (from reference)
#define NS   65536    // SAMPLES
#define XD   128      // LX*DX
#define ZD   128      // LZ*DZ
// n states = 4

typedef float f32x2 __attribute__((ext_vector_type(2)));
struct F4p { f32x2 lo, hi; };   // 16B, loads as b128

// ---------------- threefry2x32 (exact JAX semantics) ----------------
struct U2 { uint32_t x, y; };

__host__ __device__ constexpr uint32_t rotl32(uint32_t v, int r) {
  return (v << r) | (v >> (32 - r));
}

__host__ __device__ constexpr U2 threefry2x32(uint32_t k0, uint32_t k1,
                                              uint32_t x0, uint32_t x1) {
  uint32_t ks0 = k0, ks1 = k1, ks2 = k0 ^ k1 ^ 0x1BD11BDAu;
  x0 += ks0; x1 += ks1;
  x0 += x1; x1 = rotl32(x1, 13); x1 ^= x0;
  x0 += x1; x1 = rotl32(x1, 15); x1 ^= x0;
  x0 += x1; x1 = rotl32(x1, 26); x1 ^= x0;
  x0 += x1; x1 = rotl32(x1,  6); x1 ^= x0;
  x0 += ks1; x1 += ks2 + 1u;
  x0 += x1; x1 = rotl32(x1, 17); x1 ^= x0;
  x0 += x1; x1 = rotl32(x1, 29); x1 ^= x0;
  x0 += x1; x1 = rotl32(x1, 16); x1 ^= x0;
  x0 += x1; x1 = rotl32(x1, 24); x1 ^= x0;
  x0 += ks2; x1 += ks0 + 2u;
  x0 += x1; x1 = rotl32(x1, 13); x1 ^= x0;
  x0 += x1; x1 = rotl32(x1, 15); x1 ^= x0;
  x0 += x1; x1 = rotl32(x1, 26); x1 ^= x0;
  x0 += x1; x1 = rotl32(x1,  6); x1 ^= x0;
  x0 += ks0; x1 += ks1 + 3u;
  x0 += x1; x1 = rotl32(x1, 17); x1 ^= x0;
  x0 += x1; x1 = rotl32(x1, 29); x1 ^= x0;
  x0 += x1; x1 = rotl32(x1, 16); x1 ^= x0;
  x0 += x1; x1 = rotl32(x1, 24); x1 ^= x0;
  x0 += ks1; x1 += ks2 + 4u;
  x0 += x1; x1 = rotl32(x1, 13); x1 ^= x0;
  x0 += x1; x1 = rotl32(x1, 15); x1 ^= x0;
  x0 += x1; x1 = rotl32(x1, 26); x1 ^= x0;
  x0 += x1; x1 = rotl32(x1,  6); x1 ^= x0;
  x0 += ks2; x1 += ks0 + 5u;
  return {x0, x1};
}

constexpr U2 KEYZ = threefry2x32(0u, 42u, 0u, 0u);
constexpr U2 KEYX = threefry2x32(0u, 42u, 0u, 1u);
constexpr uint32_t KZ0 = KEYZ.x, KZ1 = KEYZ.y;
constexpr uint32_t KX0 = KEYX.x, KX1 = KEYX.y;

// f32 gumbel (same as jax's own f32 path; np-f64 ref differs by ~1e-7 abs)
__device__ inline float gumbel32f(uint32_t k0, uint32_t k1, uint32_t idx) {
  U2 h = threefry2x32(k0, k1, 0u, idx);
  uint32_t bits = h.x ^ h.y;
  float f = __uint_as_float((bits >> 9) | 0x3f800000u) - 1.0f;  // [0,1)
  float u = fmaxf(f, 1.1754943508222875e-38f);
  float lu = __logf(u);          // < 0
  return -__logf(-lu);
}

// Named-member accumulator: never dynamically indexed -> stays in VGPRs.
struct Acc { double v0, v1, v2, v3; };

__device__ inline double pick(const Acc& d, int i) {   // ternary chain -> cndmask
  return (i == 0) ? d.v0 : (i == 1) ? d.v1 : (i == 2) ? d.v2 : d.v3;
}

__device__ inline int argmax4(double v0, double v1, double v2, double v3) {
  int best = 0; double bv = v0;
  if (v1 > bv) { bv = v1; best = 1; }
  if (v2 > bv) { bv = v2; best = 2; }
  if (v3 > bv) { bv = v3; best = 3; }
  return best;
}

// sample one categorical (4-way) decision for output flat base index ib
__device__ inline int sample4(uint32_t k0, uint32_t k1, uint32_t ib, const Acc& d) {
  return argmax4((double)gumbel32f(k0, k1, ib + 0u) - d.v0,
                 (double)gumbel32f(k0, k1, ib + 1u) - d.v1,
                 (double)gumbel32f(k0, k1, ib + 2u) - d.v2,
                 (double)gumbel32f(k0, k1, ib + 3u) - d.v3);
}

// ---------------- kernel 0: fused pack_x0 + direct pair-table build -----------
// blocks [0, 2048): pack x0_idx to 2-bit codes
// blocks [2048, 3072): compute PZ/PX pair tables directly (no K intermediate).
// f64 expression shapes identical to the original build_k -> identical f32 bits.
__global__ __launch_bounds__(256) void setup(const int* __restrict__ x0,
                                             const float* __restrict__ biadj,
                                             const float* __restrict__ eps,
                                             const float* __restrict__ chi,
                                             uint32_t* __restrict__ pk,
                                             float4* __restrict__ PZ,
                                             float4* __restrict__ PX) {
  if (blockIdx.x < 2048) {
    int t = blockIdx.x * 256 + threadIdx.x;   // 0 .. NS*8-1
    const int4* src = (const int4*)x0 + (size_t)t * 4;  // 16 consecutive ints
    uint32_t w = 0;
#pragma unroll
    for (int i = 0; i < 4; ++i) {
      int4 v = src[i];
      w |= (uint32_t)(v.x & 3) << (8 * i + 0);
      w |= (uint32_t)(v.y & 3) << (8 * i + 2);
      w |= (uint32_t)(v.z & 3) << (8 * i + 4);
      w |= (uint32_t)(v.w & 3) << (8 * i + 6);
    }
    pk[t] = w;
  } else {
    int gid = (blockIdx.x - 2048) * 256 + threadIdx.x;  // 0 .. 262143
    int isX = gid >> 17;
    int t = gid & 131071;
    int c = t & 15, rp = (t >> 4) & 63, r = t >> 10;    // r = z or x
    int ixA, dxA, izA, dzA, ixB, dxB, izB, dzB;
    if (!isX) {               // PZ: x = 2rp / 2rp+1, z = r
      ixA = rp; dxA = 0; ixB = rp; dxB = 1;
      izA = r >> 1; dzA = r & 1; izB = izA; dzB = dzA;
    } else {                  // PX: x = r, z = 2rp / 2rp+1
      ixA = r >> 1; dxA = r & 1; ixB = ixA; dxB = dxA;
      izA = rp; dzA = 0; izB = rp; dzB = 1;
    }
    double c0A = 0.0, c1A = 0.0, c2A = 0.0, c0B = 0.0, c1B = 0.0, c2B = 0.0;
#pragma unroll
    for (int b = 0; b < 8; ++b) {
      double biA = (double)biadj[(ixA * 64 + izA) * 8 + b];
      c0A += biA * (double)eps[((b * 3 + 0) * 2 + dxA) * 2 + dzA];
      c1A += biA * (double)eps[((b * 3 + 1) * 2 + dxA) * 2 + dzA];
      c2A += biA * (double)eps[((b * 3 + 2) * 2 + dxA) * 2 + dzA];
      double biB = (double)biadj[(ixB * 64 + izB) * 8 + b];
      c0B += biB * (double)eps[((b * 3 + 0) * 2 + dxB) * 2 + dzB];
      c1B += biB * (double)eps[((b * 3 + 1) * 2 + dxB) * 2 + dzB];
      c2B += biB * (double)eps[((b * 3 + 2) * 2 + dxB) * 2 + dzB];
    }
    float out[4];
#pragma unroll
    for (int q = 0; q < 4; ++q) {
      int pqA, pqB;
      if (!isX) { pqA = (c & 3) * 4 + q; pqB = (c >> 2) * 4 + q; }   // a=c, b=q
      else      { pqA = q * 4 + (c & 3); pqB = q * 4 + (c >> 2); }   // a=q, b=c
      double kvA = c0A * (double)chi[pqA * 3 + 0]
                 + c1A * (double)chi[pqA * 3 + 1]
                 + c2A * (double)chi[pqA * 3 + 2];
      double kvB = c0B * (double)chi[pqB * 3 + 0]
                 + c1B * (double)chi[pqB * 3 + 1]
                 + c2B * (double)chi[pqB * 3 + 2];
      out[q] = (float)kvA + (float)kvB;
    }
    float4* P = isX ? PX : PZ;
    P[(r * 64 + rp) * 16 + c] = float4{out[0], out[1], out[2], out[3]};
  }
}

// ---------------- hybrid gather core: groups 0-1 from L2, groups 2-3 from LDS --
// L holds pairs 32..63 of both tables (table1 at F4p-offset +512, byte 8192).
// G0/G1 are the global table bases (wave-uniform). Summation order identical
// to rounds 3..11: f32 within 16-pair groups (packed adds), f64 across groups,
// g ascending -> bit-identical results (absmax 0.0 verified lineage).
__device__ inline void pair_accum_hyb(const F4p* __restrict__ L,
                                      const F4p* __restrict__ G0,
                                      const F4p* __restrict__ G1,
                                      const uint32_t* __restrict__ cw,
                                      Acc& dA, Acc& dB) {
#pragma unroll
  for (int g = 0; g < 2; ++g) {   // groups 0..1 via global (L2-resident)
    f32x2 a01 = {0.f, 0.f}, a23 = {0.f, 0.f};
    f32x2 b01 = {0.f, 0.f}, b23 = {0.f, 0.f};
#pragma unroll
    for (int j2 = 0; j2 < 2; ++j2) {
      uint32_t w = cw[2 * g + j2];
#pragma unroll
      for (int t = 0; t < 8; ++t) {
        int c = (w >> (4 * t)) & 15;
        int idx = (16 * g + 8 * j2 + t) * 16 + c;
        F4p e0 = G0[idx];
        F4p e1 = G1[idx];
        a01 += e0.lo; a23 += e0.hi;
        b01 += e1.lo; b23 += e1.hi;
      }
    }
    dA.v0 += (double)a01.x; dA.v1 += (double)a01.y;
    dA.v2 += (double)a23.x; dA.v3 += (double)a23.y;
    dB.v0 += (double)b01.x; dB.v1 += (double)b01.y;
    dB.v2 += (double)b23.x; dB.v3 += (double)b23.y;
  }
#pragma unroll
  for (int g = 2; g < 4; ++g) {   // groups 2..3 via LDS
    f32x2 a01 = {0.f, 0.f}, a23 = {0.f, 0.f};
    f32x2 b01 = {0.f, 0.f}, b23 = {0.f, 0.f};
#pragma unroll
    for (int j2 = 0; j2 < 2; ++j2) {
      uint32_t w = cw[2 * g + j2];
#pragma unroll
      for (int t = 0; t < 8; ++t) {
        int c = (w >> (4 * t)) & 15;
        const F4p* e = &L[(16 * (g - 2) + 8 * j2 + t) * 16 + c];
        F4p e0 = e[0];
        F4p e1 = e[512];           // second table, byte offset 8192
        a01 += e0.lo; a23 += e0.hi;
        b01 += e1.lo; b23 += e1.hi;
      }
    }
    dA.v0 += (double)a01.x; dA.v1 += (double)a01.y;
    dA.v2 += (double)a23.x; dA.v3 += (double)a23.y;
    dB.v0 += (double)b01.x; dB.v1 += (double)b01.y;
    dB.v2 += (double)b23.x; dB.v3 += (double)b23.y;
  }
}

// stage pairs 32..63 of both tables (1024 F4p = 16 KB) from P + by*2048
__device__ inline void stage_tables(const F4p* __restrict__ Pby, F4p* __restrict__ Ltab,
                                    int tid) {
  const uint4* src0 = (const uint4*)(Pby + 512);    // table0 pairs 32..63
  const uint4* src1 = (const uint4*)(Pby + 1536);   // table1 pairs 32..63
  uint4* dst = (uint4*)Ltab;
#pragma unroll
  for (int i = 0; i < 2; ++i) dst[tid + i * 256] = src0[tid + i * 256];
#pragma unroll
  for (int i = 0; i < 2; ++i) dst[512 + tid + i * 256] = src1[tid + i * 256];
}

// ---------------- kernel 1: ez + categorical(kz) for 2 z's -> zidxT[z][s] ------
__global__ __launch_bounds__(256, 8) void ez_pair(const float4* __restrict__ PZ,
                                                  const uint32_t* __restrict__ pk,
                                                  uint8_t* __restrict__ zidxT) {
  __shared__ F4p Ltab[1024];   // 16 KB -> 8 blocks/CU (32 waves = 100%)
  int tid = threadIdx.x;
  int by = blockIdx.y;
  const F4p* Pby = (const F4p*)PZ + (size_t)by * 2048;
  stage_tables(Pby, Ltab, tid);
  __syncthreads();
  int s = blockIdx.x * 256 + tid;
  uint32_t cw[8];
  {  // two 16B loads of this sample's codes
    uint4 w0 = *(const uint4*)(pk + (size_t)s * 8);
    uint4 w1 = *(const uint4*)(pk + (size_t)s * 8 + 4);
    cw[0] = w0.x; cw[1] = w0.y; cw[2] = w0.z; cw[3] = w0.w;
    cw[4] = w1.x; cw[5] = w1.y; cw[6] = w1.z; cw[7] = w1.w;
  }
  Acc dA = {0, 0, 0, 0}, dB = {0, 0, 0, 0};
  pair_accum_hyb(Ltab, Pby, Pby + 1024, cw, dA, dB);

  int z0 = 2 * by, z1 = 2 * by + 1;
  uint32_t ib = ((uint32_t)s * 128u + (uint32_t)z0) * 4u;
  zidxT[(size_t)z0 * NS + s] = (uint8_t)sample4(KZ0, KZ1, ib, dA);       // coalesced
  zidxT[(size_t)z1 * NS + s] = (uint8_t)sample4(KZ0, KZ1, ib + 4u, dB);  // coalesced
}

// ---------------- kernel 2: repack zidx bytes -> 2-bit codes zpk[j][s] --------
__global__ __launch_bounds__(256) void repack_z(const uint8_t* __restrict__ zidxT,
                                                uint32_t* __restrict__ zpk) {
  uint32_t t = blockIdx.x * 256u + threadIdx.x;  // 0 .. NS*8-1
  uint32_t j = t >> 16, s = t & 65535u;
  uint32_t w = 0;
#pragma unroll
  for (int k = 0; k < 16; ++k)
    w |= (uint32_t)zidxT[(size_t)(16 * j + k) * NS + s] << (2 * k);
  zpk[t] = w;   // zpk[j*NS + s], coalesced
}

// ---------------- kernel 3: ex + categorical(kx) + loss for 2 x's -------------
// No contended atomics: per-block f64 partial -> loss_part[16384].
__global__ __launch_bounds__(256, 8) void ex_pair(const float4* __restrict__ PX,
                                                  const uint32_t* __restrict__ zpk,
                                                  const uint32_t* __restrict__ pk,
                                                  uint8_t* __restrict__ xidxT,
                                                  double* __restrict__ loss_part) {
  __shared__ F4p Ltab[1024];   // 16 KB (reused for the loss reduce)
  int tid = threadIdx.x;
  int by = blockIdx.y;
  const F4p* Pby = (const F4p*)PX + (size_t)by * 2048;
  stage_tables(Pby, Ltab, tid);
  __syncthreads();
  int s = blockIdx.x * 256 + tid;
  uint32_t cw[8];
#pragma unroll
  for (int j = 0; j < 8; ++j) cw[j] = zpk[(size_t)j * NS + s];  // coalesced
  Acc dA = {0, 0, 0, 0}, dB = {0, 0, 0, 0};
  pair_accum_hyb(Ltab, Pby, Pby + 1024, cw, dA, dB);

  int x0 = 2 * by, x1 = 2 * by + 1;
  uint32_t ib = ((uint32_t)s * 128u + (uint32_t)x0) * 4u;
  int bestA = sample4(KX0, KX1, ib, dA);
  int bestB = sample4(KX0, KX1, ib + 4u, dB);
  xidxT[(size_t)x0 * NS + s] = (uint8_t)bestA;   // coalesced
  xidxT[(size_t)x1 * NS + s] = (uint8_t)bestB;   // coalesced

  // loss terms for both x's: ex[x0_code] - ex[sampled] (ternary selects only)
  uint32_t wj = pk[(size_t)s * 8 + (x0 >> 4)];   // both x's share this word
  int aiA = (wj >> (2 * (x0 & 15))) & 3;
  int aiB = (wj >> (2 * (x1 & 15))) & 3;
  double term = pick(dA, aiA) - pick(dA, bestA)
              + pick(dB, aiB) - pick(dB, bestB);
#pragma unroll
  for (int off = 32; off > 0; off >>= 1) term += __shfl_down(term, off, 64);
  __syncthreads();                       // all waves done reading Ltab -> reuse
  double* red = (double*)Ltab;
  if ((tid & 63) == 0) red[tid >> 6] = term;
  __syncthreads();
  if (tid == 0)
    loss_part[(size_t)by * 256 + blockIdx.x] = red[0] + red[1] + red[2] + red[3];
}

// ---------------- kernel 4: fused transpose + one-hot writeback + loss --------
// block 0 additionally reduces the 16384 per-block loss partials -> out[0].
__global__ __launch_bounds__(256) void write_out(const uint8_t* __restrict__ xidxT,
                                                 const double* __restrict__ loss_part,
                                                 float* __restrict__ out) {
  __shared__ uint8_t tile[128 * 80];   // [x][s0..s0+63], stride 80
  __shared__ double red2[4];
  int tid = threadIdx.x;
  int s0 = blockIdx.x * 64;
  {  // stage 128 x-rows of 64 s-bytes
    int x = tid >> 1, chunk = tid & 1;
    const uint8_t* src = xidxT + (size_t)x * NS + s0 + chunk * 32;
    uint4 v0 = *(const uint4*)(src);
    uint4 v1 = *(const uint4*)(src + 16);
    *(uint4*)&tile[x * 80 + chunk * 32 + 0]  = v0;
    *(uint4*)&tile[x * 80 + chunk * 32 + 16] = v1;
  }
  __syncthreads();
  float4* dst = (float4*)(out + 1 + (size_t)s0 * 512);
#pragma unroll 4
  for (int k = 0; k < 32; ++k) {
    int idx = k * 256 + tid;            // 0 .. 8191 = (sl, x)
    int x = idx & 127, sl = idx >> 7;
    int b = tile[x * 80 + sl];
    dst[idx] = float4{b == 0 ? 1.0f : 0.0f, b == 1 ? 1.0f : 0.0f,
                      b == 2 ? 1.0f : 0.0f, b == 3 ? 1.0f : 0.0f};
  }
  if (blockIdx.x == 0) {                 // loss reduce (uniform within block 0)
    double p = 0.0;
#pragma unroll 4
    for (int i = tid; i < 16384; i += 256) p += loss_part[i];
#pragma unroll
    for (int off = 32; off > 0; off >>= 1) p += __shfl_down(p, off, 64);
    if ((tid & 63) == 0) red2[tid >> 6] = p;
    __syncthreads();
    if (tid == 0)
      out[0] = (float)((red2[0] + red2[1] + red2[2] + red2[3]) * (1.0 / 65536.0));
  }
}

extern "C" void kernel_launch(void* const* d_in, const int* in_sizes, int n_in,
                              void* d_out, int out_size, void* d_ws, size_t ws_size,
                              hipStream_t stream) {
  const float* biadj = (const float*)d_in[0];   // [64,64,8]
  const float* eps   = (const float*)d_in[1];   // [8,3,2,2]
  const float* chi   = (const float*)d_in[2];   // [4,4,3]
  const int*   x0    = (const int*)d_in[3];     // [65536,128]
  float* out = (float*)d_out;                   // [1 + 65536*128*4]

  // workspace layout (~24.4 MB)
  char* w = (char*)d_ws;
  double*   loss_part = (double*)w;                w += (size_t)16384 * 8;           // 128 KB
  uint32_t* pk    = (uint32_t*)w;                  w += (size_t)NS * 8 * 4;          // 2 MB
  uint8_t*  zidxT = (uint8_t*)w;                   w += (size_t)NS * ZD;             // 8 MB
  uint32_t* zpk   = (uint32_t*)w;                  w += (size_t)NS * 8 * 4;          // 2 MB
  uint8_t*  xidxT = (uint8_t*)w;                   w += (size_t)NS * XD;             // 8 MB
  float4*   PZ    = (float4*)w;                    w += (size_t)128 * 64 * 16 * 16;  // 2 MB
  float4*   PX    = (float4*)w;                    /* 2 MB */

  setup<<<3072, 256, 0, stream>>>(x0, biadj, eps, chi, pk, PZ, PX);
  ez_pair<<<dim3(NS / 256, ZD / 2), 256, 0, stream>>>(PZ, pk, zidxT);
  repack_z<<<NS * 8 / 256, 256, 0, stream>>>(zidxT, zpk);
  ex_pair<<<dim3(NS / 256, XD / 2), 256, 0, stream>>>(PX, zpk, pk, xidxT, loss_part);
  write_out<<<NS / 64, 256, 0, stream>>>(xidxT, loss_part, out);
}

// Round 13
// 524.349 us; speedup vs baseline: 1.0773x; 1.0773x over previous
//
#include <hip/hip_runtime.h>
#include <stdint.h>

// Problem constants (from reference)
#define NS   65536    // SAMPLES
#define XD   128      // LX*DX
#define ZD   128      // LZ*DZ
// n states = 4

typedef float f32x2 __attribute__((ext_vector_type(2)));
struct F4p { f32x2 lo, hi; };   // 16B, loads as b128

// ---------------- threefry2x32 (exact JAX semantics) ----------------
struct U2 { uint32_t x, y; };

__host__ __device__ constexpr uint32_t rotl32(uint32_t v, int r) {
  return (v << r) | (v >> (32 - r));
}

__host__ __device__ constexpr U2 threefry2x32(uint32_t k0, uint32_t k1,
                                              uint32_t x0, uint32_t x1) {
  uint32_t ks0 = k0, ks1 = k1, ks2 = k0 ^ k1 ^ 0x1BD11BDAu;
  x0 += ks0; x1 += ks1;
  x0 += x1; x1 = rotl32(x1, 13); x1 ^= x0;
  x0 += x1; x1 = rotl32(x1, 15); x1 ^= x0;
  x0 += x1; x1 = rotl32(x1, 26); x1 ^= x0;
  x0 += x1; x1 = rotl32(x1,  6); x1 ^= x0;
  x0 += ks1; x1 += ks2 + 1u;
  x0 += x1; x1 = rotl32(x1, 17); x1 ^= x0;
  x0 += x1; x1 = rotl32(x1, 29); x1 ^= x0;
  x0 += x1; x1 = rotl32(x1, 16); x1 ^= x0;
  x0 += x1; x1 = rotl32(x1, 24); x1 ^= x0;
  x0 += ks2; x1 += ks0 + 2u;
  x0 += x1; x1 = rotl32(x1, 13); x1 ^= x0;
  x0 += x1; x1 = rotl32(x1, 15); x1 ^= x0;
  x0 += x1; x1 = rotl32(x1, 26); x1 ^= x0;
  x0 += x1; x1 = rotl32(x1,  6); x1 ^= x0;
  x0 += ks0; x1 += ks1 + 3u;
  x0 += x1; x1 = rotl32(x1, 17); x1 ^= x0;
  x0 += x1; x1 = rotl32(x1, 29); x1 ^= x0;
  x0 += x1; x1 = rotl32(x1, 16); x1 ^= x0;
  x0 += x1; x1 = rotl32(x1, 24); x1 ^= x0;
  x0 += ks1; x1 += ks2 + 4u;
  x0 += x1; x1 = rotl32(x1, 13); x1 ^= x0;
  x0 += x1; x1 = rotl32(x1, 15); x1 ^= x0;
  x0 += x1; x1 = rotl32(x1, 26); x1 ^= x0;
  x0 += x1; x1 = rotl32(x1,  6); x1 ^= x0;
  x0 += ks2; x1 += ks0 + 5u;
  return {x0, x1};
}

constexpr U2 KEYZ = threefry2x32(0u, 42u, 0u, 0u);
constexpr U2 KEYX = threefry2x32(0u, 42u, 0u, 1u);
constexpr uint32_t KZ0 = KEYZ.x, KZ1 = KEYZ.y;
constexpr uint32_t KX0 = KEYX.x, KX1 = KEYX.y;

// f32 gumbel (same as jax's own f32 path; np-f64 ref differs by ~1e-7 abs)
__device__ inline float gumbel32f(uint32_t k0, uint32_t k1, uint32_t idx) {
  U2 h = threefry2x32(k0, k1, 0u, idx);
  uint32_t bits = h.x ^ h.y;
  float f = __uint_as_float((bits >> 9) | 0x3f800000u) - 1.0f;  // [0,1)
  float u = fmaxf(f, 1.1754943508222875e-38f);
  float lu = __logf(u);          // < 0
  return -__logf(-lu);
}

// Named-member accumulator: never dynamically indexed -> stays in VGPRs.
struct Acc { double v0, v1, v2, v3; };

__device__ inline double pick(const Acc& d, int i) {   // ternary chain -> cndmask
  return (i == 0) ? d.v0 : (i == 1) ? d.v1 : (i == 2) ? d.v2 : d.v3;
}

__device__ inline int argmax4(double v0, double v1, double v2, double v3) {
  int best = 0; double bv = v0;
  if (v1 > bv) { bv = v1; best = 1; }
  if (v2 > bv) { bv = v2; best = 2; }
  if (v3 > bv) { bv = v3; best = 3; }
  return best;
}

// sample one categorical (4-way) decision for output flat base index ib
__device__ inline int sample4(uint32_t k0, uint32_t k1, uint32_t ib, const Acc& d) {
  return argmax4((double)gumbel32f(k0, k1, ib + 0u) - d.v0,
                 (double)gumbel32f(k0, k1, ib + 1u) - d.v1,
                 (double)gumbel32f(k0, k1, ib + 2u) - d.v2,
                 (double)gumbel32f(k0, k1, ib + 3u) - d.v3);
}

// ---------------- kernel 0: fused pack_x0 + direct pair-table build -----------
// blocks [0, 2048): pack x0_idx to 2-bit codes
// blocks [2048, 3072): compute PZ/PX pair tables directly (no K intermediate).
// f64 expression shapes identical to the original build_k -> identical f32 bits.
__global__ __launch_bounds__(256) void setup(const int* __restrict__ x0,
                                             const float* __restrict__ biadj,
                                             const float* __restrict__ eps,
                                             const float* __restrict__ chi,
                                             uint32_t* __restrict__ pk,
                                             float4* __restrict__ PZ,
                                             float4* __restrict__ PX) {
  if (blockIdx.x < 2048) {
    int t = blockIdx.x * 256 + threadIdx.x;   // 0 .. NS*8-1
    const int4* src = (const int4*)x0 + (size_t)t * 4;  // 16 consecutive ints
    uint32_t w = 0;
#pragma unroll
    for (int i = 0; i < 4; ++i) {
      int4 v = src[i];
      w |= (uint32_t)(v.x & 3) << (8 * i + 0);
      w |= (uint32_t)(v.y & 3) << (8 * i + 2);
      w |= (uint32_t)(v.z & 3) << (8 * i + 4);
      w |= (uint32_t)(v.w & 3) << (8 * i + 6);
    }
    pk[t] = w;
  } else {
    int gid = (blockIdx.x - 2048) * 256 + threadIdx.x;  // 0 .. 262143
    int isX = gid >> 17;
    int t = gid & 131071;
    int c = t & 15, rp = (t >> 4) & 63, r = t >> 10;    // r = z or x
    int ixA, dxA, izA, dzA, ixB, dxB, izB, dzB;
    if (!isX) {               // PZ: x = 2rp / 2rp+1, z = r
      ixA = rp; dxA = 0; ixB = rp; dxB = 1;
      izA = r >> 1; dzA = r & 1; izB = izA; dzB = dzA;
    } else {                  // PX: x = r, z = 2rp / 2rp+1
      ixA = r >> 1; dxA = r & 1; ixB = ixA; dxB = dxA;
      izA = rp; dzA = 0; izB = rp; dzB = 1;
    }
    double c0A = 0.0, c1A = 0.0, c2A = 0.0, c0B = 0.0, c1B = 0.0, c2B = 0.0;
#pragma unroll
    for (int b = 0; b < 8; ++b) {
      double biA = (double)biadj[(ixA * 64 + izA) * 8 + b];
      c0A += biA * (double)eps[((b * 3 + 0) * 2 + dxA) * 2 + dzA];
      c1A += biA * (double)eps[((b * 3 + 1) * 2 + dxA) * 2 + dzA];
      c2A += biA * (double)eps[((b * 3 + 2) * 2 + dxA) * 2 + dzA];
      double biB = (double)biadj[(ixB * 64 + izB) * 8 + b];
      c0B += biB * (double)eps[((b * 3 + 0) * 2 + dxB) * 2 + dzB];
      c1B += biB * (double)eps[((b * 3 + 1) * 2 + dxB) * 2 + dzB];
      c2B += biB * (double)eps[((b * 3 + 2) * 2 + dxB) * 2 + dzB];
    }
    float out[4];
#pragma unroll
    for (int q = 0; q < 4; ++q) {
      int pqA, pqB;
      if (!isX) { pqA = (c & 3) * 4 + q; pqB = (c >> 2) * 4 + q; }   // a=c, b=q
      else      { pqA = q * 4 + (c & 3); pqB = q * 4 + (c >> 2); }   // a=q, b=c
      double kvA = c0A * (double)chi[pqA * 3 + 0]
                 + c1A * (double)chi[pqA * 3 + 1]
                 + c2A * (double)chi[pqA * 3 + 2];
      double kvB = c0B * (double)chi[pqB * 3 + 0]
                 + c1B * (double)chi[pqB * 3 + 1]
                 + c2B * (double)chi[pqB * 3 + 2];
      out[q] = (float)kvA + (float)kvB;
    }
    float4* P = isX ? PX : PZ;
    P[(r * 64 + rp) * 16 + c] = float4{out[0], out[1], out[2], out[3]};
  }
}

// ---------------- hybrid gather core: groups 0-1 from L2, groups 2-3 from LDS --
// L holds pairs 32..63 of both tables (table1 at F4p-offset +512, byte 8192).
// G0/G1 are the global table bases (wave-uniform). Summation order identical
// to rounds 3..12: f32 within 16-pair groups (packed adds), f64 across groups,
// g ascending -> bit-identical results (absmax 0.0 verified lineage).
__device__ inline void pair_accum_hyb(const F4p* __restrict__ L,
                                      const F4p* __restrict__ G0,
                                      const F4p* __restrict__ G1,
                                      const uint32_t* __restrict__ cw,
                                      Acc& dA, Acc& dB) {
#pragma unroll
  for (int g = 0; g < 2; ++g) {   // groups 0..1 via global (L2-resident)
    f32x2 a01 = {0.f, 0.f}, a23 = {0.f, 0.f};
    f32x2 b01 = {0.f, 0.f}, b23 = {0.f, 0.f};
#pragma unroll
    for (int j2 = 0; j2 < 2; ++j2) {
      uint32_t w = cw[2 * g + j2];
#pragma unroll
      for (int t = 0; t < 8; ++t) {
        int c = (w >> (4 * t)) & 15;
        int idx = (16 * g + 8 * j2 + t) * 16 + c;
        F4p e0 = G0[idx];
        F4p e1 = G1[idx];
        a01 += e0.lo; a23 += e0.hi;
        b01 += e1.lo; b23 += e1.hi;
      }
    }
    dA.v0 += (double)a01.x; dA.v1 += (double)a01.y;
    dA.v2 += (double)a23.x; dA.v3 += (double)a23.y;
    dB.v0 += (double)b01.x; dB.v1 += (double)b01.y;
    dB.v2 += (double)b23.x; dB.v3 += (double)b23.y;
  }
#pragma unroll
  for (int g = 2; g < 4; ++g) {   // groups 2..3 via LDS
    f32x2 a01 = {0.f, 0.f}, a23 = {0.f, 0.f};
    f32x2 b01 = {0.f, 0.f}, b23 = {0.f, 0.f};
#pragma unroll
    for (int j2 = 0; j2 < 2; ++j2) {
      uint32_t w = cw[2 * g + j2];
#pragma unroll
      for (int t = 0; t < 8; ++t) {
        int c = (w >> (4 * t)) & 15;
        const F4p* e = &L[(16 * (g - 2) + 8 * j2 + t) * 16 + c];
        F4p e0 = e[0];
        F4p e1 = e[512];           // second table, byte offset 8192
        a01 += e0.lo; a23 += e0.hi;
        b01 += e1.lo; b23 += e1.hi;
      }
    }
    dA.v0 += (double)a01.x; dA.v1 += (double)a01.y;
    dA.v2 += (double)a23.x; dA.v3 += (double)a23.y;
    dB.v0 += (double)b01.x; dB.v1 += (double)b01.y;
    dB.v2 += (double)b23.x; dB.v3 += (double)b23.y;
  }
}

// stage pairs 32..63 of both tables (1024 F4p = 16 KB) from P + by*2048
__device__ inline void stage_tables(const F4p* __restrict__ Pby, F4p* __restrict__ Ltab,
                                    int tid) {
  const uint4* src0 = (const uint4*)(Pby + 512);    // table0 pairs 32..63
  const uint4* src1 = (const uint4*)(Pby + 1536);   // table1 pairs 32..63
  uint4* dst = (uint4*)Ltab;
#pragma unroll
  for (int i = 0; i < 2; ++i) dst[tid + i * 256] = src0[tid + i * 256];
#pragma unroll
  for (int i = 0; i < 2; ++i) dst[512 + tid + i * 256] = src1[tid + i * 256];
}

// ---------------- kernel 1: ez + categorical(kz) for 2 z's -> zidxT[z][s] ------
// bound 6 (VGPR cap ~84): allocator fits ~40-52 regs WITHOUT spilling; at that
// count HW reaches 8 blocks/CU on its own (16 KB LDS). Bound 8 forced spills (r12).
__global__ __launch_bounds__(256, 6) void ez_pair(const float4* __restrict__ PZ,
                                                  const uint32_t* __restrict__ pk,
                                                  uint8_t* __restrict__ zidxT) {
  __shared__ F4p Ltab[1024];   // 16 KB
  int tid = threadIdx.x;
  int by = blockIdx.y;
  const F4p* Pby = (const F4p*)PZ + (size_t)by * 2048;
  stage_tables(Pby, Ltab, tid);
  __syncthreads();
  int s = blockIdx.x * 256 + tid;
  uint32_t cw[8];
  {  // two 16B loads of this sample's codes
    uint4 w0 = *(const uint4*)(pk + (size_t)s * 8);
    uint4 w1 = *(const uint4*)(pk + (size_t)s * 8 + 4);
    cw[0] = w0.x; cw[1] = w0.y; cw[2] = w0.z; cw[3] = w0.w;
    cw[4] = w1.x; cw[5] = w1.y; cw[6] = w1.z; cw[7] = w1.w;
  }
  Acc dA = {0, 0, 0, 0}, dB = {0, 0, 0, 0};
  pair_accum_hyb(Ltab, Pby, Pby + 1024, cw, dA, dB);

  int z0 = 2 * by, z1 = 2 * by + 1;
  uint32_t ib = ((uint32_t)s * 128u + (uint32_t)z0) * 4u;
  zidxT[(size_t)z0 * NS + s] = (uint8_t)sample4(KZ0, KZ1, ib, dA);       // coalesced
  zidxT[(size_t)z1 * NS + s] = (uint8_t)sample4(KZ0, KZ1, ib + 4u, dB);  // coalesced
}

// ---------------- kernel 2: repack zidx bytes -> 2-bit codes zpk[j][s] --------
__global__ __launch_bounds__(256) void repack_z(const uint8_t* __restrict__ zidxT,
                                                uint32_t* __restrict__ zpk) {
  uint32_t t = blockIdx.x * 256u + threadIdx.x;  // 0 .. NS*8-1
  uint32_t j = t >> 16, s = t & 65535u;
  uint32_t w = 0;
#pragma unroll
  for (int k = 0; k < 16; ++k)
    w |= (uint32_t)zidxT[(size_t)(16 * j + k) * NS + s] << (2 * k);
  zpk[t] = w;   // zpk[j*NS + s], coalesced
}

// ---------------- kernel 3: ex + categorical(kx) + loss for 2 x's -------------
// No contended atomics: per-block f64 partial -> loss_part[16384].
__global__ __launch_bounds__(256, 6) void ex_pair(const float4* __restrict__ PX,
                                                  const uint32_t* __restrict__ zpk,
                                                  const uint32_t* __restrict__ pk,
                                                  uint8_t* __restrict__ xidxT,
                                                  double* __restrict__ loss_part) {
  __shared__ F4p Ltab[1024];   // 16 KB (reused for the loss reduce)
  int tid = threadIdx.x;
  int by = blockIdx.y;
  const F4p* Pby = (const F4p*)PX + (size_t)by * 2048;
  stage_tables(Pby, Ltab, tid);
  __syncthreads();
  int s = blockIdx.x * 256 + tid;
  uint32_t cw[8];
#pragma unroll
  for (int j = 0; j < 8; ++j) cw[j] = zpk[(size_t)j * NS + s];  // coalesced
  Acc dA = {0, 0, 0, 0}, dB = {0, 0, 0, 0};
  pair_accum_hyb(Ltab, Pby, Pby + 1024, cw, dA, dB);

  int x0 = 2 * by, x1 = 2 * by + 1;
  uint32_t ib = ((uint32_t)s * 128u + (uint32_t)x0) * 4u;
  int bestA = sample4(KX0, KX1, ib, dA);
  int bestB = sample4(KX0, KX1, ib + 4u, dB);
  xidxT[(size_t)x0 * NS + s] = (uint8_t)bestA;   // coalesced
  xidxT[(size_t)x1 * NS + s] = (uint8_t)bestB;   // coalesced

  // loss terms for both x's: ex[x0_code] - ex[sampled] (ternary selects only)
  uint32_t wj = pk[(size_t)s * 8 + (x0 >> 4)];   // both x's share this word
  int aiA = (wj >> (2 * (x0 & 15))) & 3;
  int aiB = (wj >> (2 * (x1 & 15))) & 3;
  double term = pick(dA, aiA) - pick(dA, bestA)
              + pick(dB, aiB) - pick(dB, bestB);
#pragma unroll
  for (int off = 32; off > 0; off >>= 1) term += __shfl_down(term, off, 64);
  __syncthreads();                       // all waves done reading Ltab -> reuse
  double* red = (double*)Ltab;
  if ((tid & 63) == 0) red[tid >> 6] = term;
  __syncthreads();
  if (tid == 0)
    loss_part[(size_t)by * 256 + blockIdx.x] = red[0] + red[1] + red[2] + red[3];
}

// ---------------- kernel 4: fused transpose + one-hot writeback + loss --------
// block 0 additionally reduces the 16384 per-block loss partials -> out[0].
__global__ __launch_bounds__(256) void write_out(const uint8_t* __restrict__ xidxT,
                                                 const double* __restrict__ loss_part,
                                                 float* __restrict__ out) {
  __shared__ uint8_t tile[128 * 80];   // [x][s0..s0+63], stride 80
  __shared__ double red2[4];
  int tid = threadIdx.x;
  int s0 = blockIdx.x * 64;
  {  // stage 128 x-rows of 64 s-bytes
    int x = tid >> 1, chunk = tid & 1;
    const uint8_t* src = xidxT + (size_t)x * NS + s0 + chunk * 32;
    uint4 v0 = *(const uint4*)(src);
    uint4 v1 = *(const uint4*)(src + 16);
    *(uint4*)&tile[x * 80 + chunk * 32 + 0]  = v0;
    *(uint4*)&tile[x * 80 + chunk * 32 + 16] = v1;
  }
  __syncthreads();
  float4* dst = (float4*)(out + 1 + (size_t)s0 * 512);
#pragma unroll 4
  for (int k = 0; k < 32; ++k) {
    int idx = k * 256 + tid;            // 0 .. 8191 = (sl, x)
    int x = idx & 127, sl = idx >> 7;
    int b = tile[x * 80 + sl];
    dst[idx] = float4{b == 0 ? 1.0f : 0.0f, b == 1 ? 1.0f : 0.0f,
                      b == 2 ? 1.0f : 0.0f, b == 3 ? 1.0f : 0.0f};
  }
  if (blockIdx.x == 0) {                 // loss reduce (uniform within block 0)
    double p = 0.0;
#pragma unroll 4
    for (int i = tid; i < 16384; i += 256) p += loss_part[i];
#pragma unroll
    for (int off = 32; off > 0; off >>= 1) p += __shfl_down(p, off, 64);
    if ((tid & 63) == 0) red2[tid >> 6] = p;
    __syncthreads();
    if (tid == 0)
      out[0] = (float)((red2[0] + red2[1] + red2[2] + red2[3]) * (1.0 / 65536.0));
  }
}

extern "C" void kernel_launch(void* const* d_in, const int* in_sizes, int n_in,
                              void* d_out, int out_size, void* d_ws, size_t ws_size,
                              hipStream_t stream) {
  const float* biadj = (const float*)d_in[0];   // [64,64,8]
  const float* eps   = (const float*)d_in[1];   // [8,3,2,2]
  const float* chi   = (const float*)d_in[2];   // [4,4,3]
  const int*   x0    = (const int*)d_in[3];     // [65536,128]
  float* out = (float*)d_out;                   // [1 + 65536*128*4]

  // workspace layout (~24.4 MB)
  char* w = (char*)d_ws;
  double*   loss_part = (double*)w;                w += (size_t)16384 * 8;           // 128 KB
  uint32_t* pk    = (uint32_t*)w;                  w += (size_t)NS * 8 * 4;          // 2 MB
  uint8_t*  zidxT = (uint8_t*)w;                   w += (size_t)NS * ZD;             // 8 MB
  uint32_t* zpk   = (uint32_t*)w;                  w += (size_t)NS * 8 * 4;          // 2 MB
  uint8_t*  xidxT = (uint8_t*)w;                   w += (size_t)NS * XD;             // 8 MB
  float4*   PZ    = (float4*)w;                    w += (size_t)128 * 64 * 16 * 16;  // 2 MB
  float4*   PX    = (float4*)w;                    /* 2 MB */

  setup<<<3072, 256, 0, stream>>>(x0, biadj, eps, chi, pk, PZ, PX);
  ez_pair<<<dim3(NS / 256, ZD / 2), 256, 0, stream>>>(PZ, pk, zidxT);
  repack_z<<<NS * 8 / 256, 256, 0, stream>>>(zidxT, zpk);
  ex_pair<<<dim3(NS / 256, XD / 2), 256, 0, stream>>>(PX, zpk, pk, xidxT, loss_part);
  write_out<<<NS / 64, 256, 0, stream>>>(xidxT, loss_part, out);
}

// Round 14
// 469.559 us; speedup vs baseline: 1.2030x; 1.1167x over previous
//
#include <hip/hip_runtime.h>
#include <stdint.h>

// Problem constants (from reference)
#define NS   65536    // SAMPLES
#define XD   128      // LX*DX
#define ZD   128      // LZ*DZ
// n states = 4

typedef float f32x2 __attribute__((ext_vector_type(2)));
struct F4p { f32x2 lo, hi; };   // 16B, loads as b128

// ---------------- threefry2x32 (exact JAX semantics) ----------------
struct U2 { uint32_t x, y; };

__host__ __device__ constexpr uint32_t rotl32(uint32_t v, int r) {
  return (v << r) | (v >> (32 - r));
}

__host__ __device__ constexpr U2 threefry2x32(uint32_t k0, uint32_t k1,
                                              uint32_t x0, uint32_t x1) {
  uint32_t ks0 = k0, ks1 = k1, ks2 = k0 ^ k1 ^ 0x1BD11BDAu;
  x0 += ks0; x1 += ks1;
  x0 += x1; x1 = rotl32(x1, 13); x1 ^= x0;
  x0 += x1; x1 = rotl32(x1, 15); x1 ^= x0;
  x0 += x1; x1 = rotl32(x1, 26); x1 ^= x0;
  x0 += x1; x1 = rotl32(x1,  6); x1 ^= x0;
  x0 += ks1; x1 += ks2 + 1u;
  x0 += x1; x1 = rotl32(x1, 17); x1 ^= x0;
  x0 += x1; x1 = rotl32(x1, 29); x1 ^= x0;
  x0 += x1; x1 = rotl32(x1, 16); x1 ^= x0;
  x0 += x1; x1 = rotl32(x1, 24); x1 ^= x0;
  x0 += ks2; x1 += ks0 + 2u;
  x0 += x1; x1 = rotl32(x1, 13); x1 ^= x0;
  x0 += x1; x1 = rotl32(x1, 15); x1 ^= x0;
  x0 += x1; x1 = rotl32(x1, 26); x1 ^= x0;
  x0 += x1; x1 = rotl32(x1,  6); x1 ^= x0;
  x0 += ks0; x1 += ks1 + 3u;
  x0 += x1; x1 = rotl32(x1, 17); x1 ^= x0;
  x0 += x1; x1 = rotl32(x1, 29); x1 ^= x0;
  x0 += x1; x1 = rotl32(x1, 16); x1 ^= x0;
  x0 += x1; x1 = rotl32(x1, 24); x1 ^= x0;
  x0 += ks1; x1 += ks2 + 4u;
  x0 += x1; x1 = rotl32(x1, 13); x1 ^= x0;
  x0 += x1; x1 = rotl32(x1, 15); x1 ^= x0;
  x0 += x1; x1 = rotl32(x1, 26); x1 ^= x0;
  x0 += x1; x1 = rotl32(x1,  6); x1 ^= x0;
  x0 += ks2; x1 += ks0 + 5u;
  return {x0, x1};
}

constexpr U2 KEYZ = threefry2x32(0u, 42u, 0u, 0u);
constexpr U2 KEYX = threefry2x32(0u, 42u, 0u, 1u);
constexpr uint32_t KZ0 = KEYZ.x, KZ1 = KEYZ.y;
constexpr uint32_t KX0 = KEYX.x, KX1 = KEYX.y;

// f32 gumbel (same as jax's own f32 path; np-f64 ref differs by ~1e-7 abs)
__device__ inline float gumbel32f(uint32_t k0, uint32_t k1, uint32_t idx) {
  U2 h = threefry2x32(k0, k1, 0u, idx);
  uint32_t bits = h.x ^ h.y;
  float f = __uint_as_float((bits >> 9) | 0x3f800000u) - 1.0f;  // [0,1)
  float u = fmaxf(f, 1.1754943508222875e-38f);
  float lu = __logf(u);          // < 0
  return -__logf(-lu);
}

// Named-member accumulator: never dynamically indexed -> stays in VGPRs.
struct Acc { double v0, v1, v2, v3; };

__device__ inline double pick(const Acc& d, int i) {   // ternary chain -> cndmask
  return (i == 0) ? d.v0 : (i == 1) ? d.v1 : (i == 2) ? d.v2 : d.v3;
}

__device__ inline int argmax4(double v0, double v1, double v2, double v3) {
  int best = 0; double bv = v0;
  if (v1 > bv) { bv = v1; best = 1; }
  if (v2 > bv) { bv = v2; best = 2; }
  if (v3 > bv) { bv = v3; best = 3; }
  return best;
}

// sample one categorical (4-way) decision for output flat base index ib
__device__ inline int sample4(uint32_t k0, uint32_t k1, uint32_t ib, const Acc& d) {
  return argmax4((double)gumbel32f(k0, k1, ib + 0u) - d.v0,
                 (double)gumbel32f(k0, k1, ib + 1u) - d.v1,
                 (double)gumbel32f(k0, k1, ib + 2u) - d.v2,
                 (double)gumbel32f(k0, k1, ib + 3u) - d.v3);
}

// ---------------- kernel 0: fused pack_x0 + direct pair-table build -----------
// blocks [0, 2048): pack x0_idx to 2-bit codes
// blocks [2048, 3072): compute PZ/PX pair tables directly (no K intermediate).
// f64 expression shapes identical to the original build_k -> identical f32 bits.
__global__ __launch_bounds__(256) void setup(const int* __restrict__ x0,
                                             const float* __restrict__ biadj,
                                             const float* __restrict__ eps,
                                             const float* __restrict__ chi,
                                             uint32_t* __restrict__ pk,
                                             float4* __restrict__ PZ,
                                             float4* __restrict__ PX) {
  if (blockIdx.x < 2048) {
    int t = blockIdx.x * 256 + threadIdx.x;   // 0 .. NS*8-1
    const int4* src = (const int4*)x0 + (size_t)t * 4;  // 16 consecutive ints
    uint32_t w = 0;
#pragma unroll
    for (int i = 0; i < 4; ++i) {
      int4 v = src[i];
      w |= (uint32_t)(v.x & 3) << (8 * i + 0);
      w |= (uint32_t)(v.y & 3) << (8 * i + 2);
      w |= (uint32_t)(v.z & 3) << (8 * i + 4);
      w |= (uint32_t)(v.w & 3) << (8 * i + 6);
    }
    pk[t] = w;
  } else {
    int gid = (blockIdx.x - 2048) * 256 + threadIdx.x;  // 0 .. 262143
    int isX = gid >> 17;
    int t = gid & 131071;
    int c = t & 15, rp = (t >> 4) & 63, r = t >> 10;    // r = z or x
    int ixA, dxA, izA, dzA, ixB, dxB, izB, dzB;
    if (!isX) {               // PZ: x = 2rp / 2rp+1, z = r
      ixA = rp; dxA = 0; ixB = rp; dxB = 1;
      izA = r >> 1; dzA = r & 1; izB = izA; dzB = dzA;
    } else {                  // PX: x = r, z = 2rp / 2rp+1
      ixA = r >> 1; dxA = r & 1; ixB = ixA; dxB = dxA;
      izA = rp; dzA = 0; izB = rp; dzB = 1;
    }
    double c0A = 0.0, c1A = 0.0, c2A = 0.0, c0B = 0.0, c1B = 0.0, c2B = 0.0;
#pragma unroll
    for (int b = 0; b < 8; ++b) {
      double biA = (double)biadj[(ixA * 64 + izA) * 8 + b];
      c0A += biA * (double)eps[((b * 3 + 0) * 2 + dxA) * 2 + dzA];
      c1A += biA * (double)eps[((b * 3 + 1) * 2 + dxA) * 2 + dzA];
      c2A += biA * (double)eps[((b * 3 + 2) * 2 + dxA) * 2 + dzA];
      double biB = (double)biadj[(ixB * 64 + izB) * 8 + b];
      c0B += biB * (double)eps[((b * 3 + 0) * 2 + dxB) * 2 + dzB];
      c1B += biB * (double)eps[((b * 3 + 1) * 2 + dxB) * 2 + dzB];
      c2B += biB * (double)eps[((b * 3 + 2) * 2 + dxB) * 2 + dzB];
    }
    float out[4];
#pragma unroll
    for (int q = 0; q < 4; ++q) {
      int pqA, pqB;
      if (!isX) { pqA = (c & 3) * 4 + q; pqB = (c >> 2) * 4 + q; }   // a=c, b=q
      else      { pqA = q * 4 + (c & 3); pqB = q * 4 + (c >> 2); }   // a=q, b=c
      double kvA = c0A * (double)chi[pqA * 3 + 0]
                 + c1A * (double)chi[pqA * 3 + 1]
                 + c2A * (double)chi[pqA * 3 + 2];
      double kvB = c0B * (double)chi[pqB * 3 + 0]
                 + c1B * (double)chi[pqB * 3 + 1]
                 + c2B * (double)chi[pqB * 3 + 2];
      out[q] = (float)kvA + (float)kvB;
    }
    float4* P = isX ? PX : PZ;
    P[(r * 64 + rp) * 16 + c] = float4{out[0], out[1], out[2], out[3]};
  }
}

// ---------------- hybrid gather core: group 0 from L1/L2, groups 1-3 from LDS --
// L holds pairs 16..63 of both tables (table1 at F4p-offset +768, byte 12288).
// G0/G1 are the global table bases (wave-uniform). Summation order identical
// to rounds 3..13: f32 within 16-pair groups (packed adds), f64 across groups,
// g ascending -> bit-identical results (absmax 0.0 verified lineage).
__device__ inline void pair_accum_hyb(const F4p* __restrict__ L,
                                      const F4p* __restrict__ G0,
                                      const F4p* __restrict__ G1,
                                      const uint32_t* __restrict__ cw,
                                      Acc& dA, Acc& dB) {
  {  // group 0 (pairs 0..15) via global, L1/L2-resident
    f32x2 a01 = {0.f, 0.f}, a23 = {0.f, 0.f};
    f32x2 b01 = {0.f, 0.f}, b23 = {0.f, 0.f};
#pragma unroll
    for (int j2 = 0; j2 < 2; ++j2) {
      uint32_t w = cw[j2];
#pragma unroll
      for (int t = 0; t < 8; ++t) {
        int c = (w >> (4 * t)) & 15;
        int idx = (8 * j2 + t) * 16 + c;
        F4p e0 = G0[idx];
        F4p e1 = G1[idx];
        a01 += e0.lo; a23 += e0.hi;
        b01 += e1.lo; b23 += e1.hi;
      }
    }
    dA.v0 += (double)a01.x; dA.v1 += (double)a01.y;
    dA.v2 += (double)a23.x; dA.v3 += (double)a23.y;
    dB.v0 += (double)b01.x; dB.v1 += (double)b01.y;
    dB.v2 += (double)b23.x; dB.v3 += (double)b23.y;
  }
#pragma unroll
  for (int g = 1; g < 4; ++g) {   // groups 1..3 via LDS
    f32x2 a01 = {0.f, 0.f}, a23 = {0.f, 0.f};
    f32x2 b01 = {0.f, 0.f}, b23 = {0.f, 0.f};
#pragma unroll
    for (int j2 = 0; j2 < 2; ++j2) {
      uint32_t w = cw[2 * g + j2];
#pragma unroll
      for (int t = 0; t < 8; ++t) {
        int c = (w >> (4 * t)) & 15;
        const F4p* e = &L[(16 * (g - 1) + 8 * j2 + t) * 16 + c];
        F4p e0 = e[0];
        F4p e1 = e[768];           // second table, byte offset 12288
        a01 += e0.lo; a23 += e0.hi;
        b01 += e1.lo; b23 += e1.hi;
      }
    }
    dA.v0 += (double)a01.x; dA.v1 += (double)a01.y;
    dA.v2 += (double)a23.x; dA.v3 += (double)a23.y;
    dB.v0 += (double)b01.x; dB.v1 += (double)b01.y;
    dB.v2 += (double)b23.x; dB.v3 += (double)b23.y;
  }
}

// stage pairs 16..63 of both tables (1536 F4p = 24 KB) from P + by*2048
__device__ inline void stage_tables(const F4p* __restrict__ Pby, F4p* __restrict__ Ltab,
                                    int tid) {
  const uint4* src0 = (const uint4*)(Pby + 256);    // table0 pairs 16..63
  const uint4* src1 = (const uint4*)(Pby + 1280);   // table1 pairs 16..63
  uint4* dst = (uint4*)Ltab;
#pragma unroll
  for (int i = 0; i < 3; ++i) dst[tid + i * 256] = src0[tid + i * 256];
#pragma unroll
  for (int i = 0; i < 3; ++i) dst[768 + tid + i * 256] = src1[tid + i * 256];
}

// ---------------- kernel 1: ez + categorical(kz) for 2 z's -> zidxT[z][s] ------
__global__ __launch_bounds__(256, 6) void ez_pair(const float4* __restrict__ PZ,
                                                  const uint32_t* __restrict__ pk,
                                                  uint8_t* __restrict__ zidxT) {
  __shared__ F4p Ltab[1536];   // 24 KB -> 6 blocks/CU
  int tid = threadIdx.x;
  int by = blockIdx.y;
  const F4p* Pby = (const F4p*)PZ + (size_t)by * 2048;
  stage_tables(Pby, Ltab, tid);
  __syncthreads();
  int s = blockIdx.x * 256 + tid;
  uint32_t cw[8];
  {  // two 16B loads of this sample's codes
    uint4 w0 = *(const uint4*)(pk + (size_t)s * 8);
    uint4 w1 = *(const uint4*)(pk + (size_t)s * 8 + 4);
    cw[0] = w0.x; cw[1] = w0.y; cw[2] = w0.z; cw[3] = w0.w;
    cw[4] = w1.x; cw[5] = w1.y; cw[6] = w1.z; cw[7] = w1.w;
  }
  Acc dA = {0, 0, 0, 0}, dB = {0, 0, 0, 0};
  pair_accum_hyb(Ltab, Pby, Pby + 1024, cw, dA, dB);

  int z0 = 2 * by, z1 = 2 * by + 1;
  uint32_t ib = ((uint32_t)s * 128u + (uint32_t)z0) * 4u;
  zidxT[(size_t)z0 * NS + s] = (uint8_t)sample4(KZ0, KZ1, ib, dA);       // coalesced
  zidxT[(size_t)z1 * NS + s] = (uint8_t)sample4(KZ0, KZ1, ib + 4u, dB);  // coalesced
}

// ---------------- kernel 2: repack zidx bytes -> 2-bit codes zpk[j][s] --------
__global__ __launch_bounds__(256) void repack_z(const uint8_t* __restrict__ zidxT,
                                                uint32_t* __restrict__ zpk) {
  uint32_t t = blockIdx.x * 256u + threadIdx.x;  // 0 .. NS*8-1
  uint32_t j = t >> 16, s = t & 65535u;
  uint32_t w = 0;
#pragma unroll
  for (int k = 0; k < 16; ++k)
    w |= (uint32_t)zidxT[(size_t)(16 * j + k) * NS + s] << (2 * k);
  zpk[t] = w;   // zpk[j*NS + s], coalesced
}

// ---------------- kernel 3: ex + categorical(kx) + loss for 2 x's -------------
// No contended atomics: per-block f64 partial -> loss_part[16384].
__global__ __launch_bounds__(256, 6) void ex_pair(const float4* __restrict__ PX,
                                                  const uint32_t* __restrict__ zpk,
                                                  const uint32_t* __restrict__ pk,
                                                  uint8_t* __restrict__ xidxT,
                                                  double* __restrict__ loss_part) {
  __shared__ F4p Ltab[1536];   // 24 KB (reused for the loss reduce)
  int tid = threadIdx.x;
  int by = blockIdx.y;
  const F4p* Pby = (const F4p*)PX + (size_t)by * 2048;
  stage_tables(Pby, Ltab, tid);
  __syncthreads();
  int s = blockIdx.x * 256 + tid;
  uint32_t cw[8];
#pragma unroll
  for (int j = 0; j < 8; ++j) cw[j] = zpk[(size_t)j * NS + s];  // coalesced
  Acc dA = {0, 0, 0, 0}, dB = {0, 0, 0, 0};
  pair_accum_hyb(Ltab, Pby, Pby + 1024, cw, dA, dB);

  int x0 = 2 * by, x1 = 2 * by + 1;
  uint32_t ib = ((uint32_t)s * 128u + (uint32_t)x0) * 4u;
  int bestA = sample4(KX0, KX1, ib, dA);
  int bestB = sample4(KX0, KX1, ib + 4u, dB);
  xidxT[(size_t)x0 * NS + s] = (uint8_t)bestA;   // coalesced
  xidxT[(size_t)x1 * NS + s] = (uint8_t)bestB;   // coalesced

  // loss terms for both x's: ex[x0_code] - ex[sampled] (ternary selects only)
  uint32_t wj = pk[(size_t)s * 8 + (x0 >> 4)];   // both x's share this word
  int aiA = (wj >> (2 * (x0 & 15))) & 3;
  int aiB = (wj >> (2 * (x1 & 15))) & 3;
  double term = pick(dA, aiA) - pick(dA, bestA)
              + pick(dB, aiB) - pick(dB, bestB);
#pragma unroll
  for (int off = 32; off > 0; off >>= 1) term += __shfl_down(term, off, 64);
  __syncthreads();                       // all waves done reading Ltab -> reuse
  double* red = (double*)Ltab;
  if ((tid & 63) == 0) red[tid >> 6] = term;
  __syncthreads();
  if (tid == 0)
    loss_part[(size_t)by * 256 + blockIdx.x] = red[0] + red[1] + red[2] + red[3];
}

// ---------------- kernel 4: fused transpose + one-hot writeback + loss --------
// block 0 additionally reduces the 16384 per-block loss partials -> out[0].
__global__ __launch_bounds__(256) void write_out(const uint8_t* __restrict__ xidxT,
                                                 const double* __restrict__ loss_part,
                                                 float* __restrict__ out) {
  __shared__ uint8_t tile[128 * 80];   // [x][s0..s0+63], stride 80
  __shared__ double red2[4];
  int tid = threadIdx.x;
  int s0 = blockIdx.x * 64;
  {  // stage 128 x-rows of 64 s-bytes
    int x = tid >> 1, chunk = tid & 1;
    const uint8_t* src = xidxT + (size_t)x * NS + s0 + chunk * 32;
    uint4 v0 = *(const uint4*)(src);
    uint4 v1 = *(const uint4*)(src + 16);
    *(uint4*)&tile[x * 80 + chunk * 32 + 0]  = v0;
    *(uint4*)&tile[x * 80 + chunk * 32 + 16] = v1;
  }
  __syncthreads();
  float4* dst = (float4*)(out + 1 + (size_t)s0 * 512);
#pragma unroll 4
  for (int k = 0; k < 32; ++k) {
    int idx = k * 256 + tid;            // 0 .. 8191 = (sl, x)
    int x = idx & 127, sl = idx >> 7;
    int b = tile[x * 80 + sl];
    dst[idx] = float4{b == 0 ? 1.0f : 0.0f, b == 1 ? 1.0f : 0.0f,
                      b == 2 ? 1.0f : 0.0f, b == 3 ? 1.0f : 0.0f};
  }
  if (blockIdx.x == 0) {                 // loss reduce (uniform within block 0)
    double p = 0.0;
#pragma unroll 4
    for (int i = tid; i < 16384; i += 256) p += loss_part[i];
#pragma unroll
    for (int off = 32; off > 0; off >>= 1) p += __shfl_down(p, off, 64);
    if ((tid & 63) == 0) red2[tid >> 6] = p;
    __syncthreads();
    if (tid == 0)
      out[0] = (float)((red2[0] + red2[1] + red2[2] + red2[3]) * (1.0 / 65536.0));
  }
}

extern "C" void kernel_launch(void* const* d_in, const int* in_sizes, int n_in,
                              void* d_out, int out_size, void* d_ws, size_t ws_size,
                              hipStream_t stream) {
  const float* biadj = (const float*)d_in[0];   // [64,64,8]
  const float* eps   = (const float*)d_in[1];   // [8,3,2,2]
  const float* chi   = (const float*)d_in[2];   // [4,4,3]
  const int*   x0    = (const int*)d_in[3];     // [65536,128]
  float* out = (float*)d_out;                   // [1 + 65536*128*4]

  // workspace layout (~24.4 MB)
  char* w = (char*)d_ws;
  double*   loss_part = (double*)w;                w += (size_t)16384 * 8;           // 128 KB
  uint32_t* pk    = (uint32_t*)w;                  w += (size_t)NS * 8 * 4;          // 2 MB
  uint8_t*  zidxT = (uint8_t*)w;                   w += (size_t)NS * ZD;             // 8 MB
  uint32_t* zpk   = (uint32_t*)w;                  w += (size_t)NS * 8 * 4;          // 2 MB
  uint8_t*  xidxT = (uint8_t*)w;                   w += (size_t)NS * XD;             // 8 MB
  float4*   PZ    = (float4*)w;                    w += (size_t)128 * 64 * 16 * 16;  // 2 MB
  float4*   PX    = (float4*)w;                    /* 2 MB */

  setup<<<3072, 256, 0, stream>>>(x0, biadj, eps, chi, pk, PZ, PX);
  ez_pair<<<dim3(NS / 256, ZD / 2), 256, 0, stream>>>(PZ, pk, zidxT);
  repack_z<<<NS * 8 / 256, 256, 0, stream>>>(zidxT, zpk);
  ex_pair<<<dim3(NS / 256, XD / 2), 256, 0, stream>>>(PX, zpk, pk, xidxT, loss_part);
  write_out<<<NS / 64, 256, 0, stream>>>(xidxT, loss_part, out);
}